// Round 9
// baseline (2563.631 us; speedup 1.0000x reference)
//
#include <hip/hip_runtime.h>
#include <hip/hip_bf16.h>
#include <math.h>

typedef short bf16x8 __attribute__((ext_vector_type(8)));
typedef float f32x4 __attribute__((ext_vector_type(4)));
typedef __hip_bfloat16 bf16;
typedef unsigned long long ull;

#define NW 8        // row windows (= XCDs; window w runs on xcd w via bid&7)
#define BSL 32      // bucket slices per window (= CUs per XCD)
#define CAP 262144  // bucket capacity (window expects ~E/8 = 200K edges)

static __device__ __forceinline__ float bf2f(ushort u) {
    unsigned int x = ((unsigned int)u) << 16;
    return __builtin_bit_cast(float, x);
}
static __device__ __forceinline__ ushort f2bf(float f) {
    bf16 h = __float2bfloat16(f);
    return __builtin_bit_cast(ushort, h);
}

// ---------------- CSR build, phase 1: bucket edges by row-window ----------------
// One streaming pass over row/col. Wave-aggregated append: one global atomic per
// (wave, bucket) ~= 1 atomic per 8 edges. Writes are runs of consecutive int2.
__global__ __launch_bounds__(256) void k_bucket(const int* __restrict__ row,
                                                const int* __restrict__ col,
                                                int2* __restrict__ bkt,
                                                int* __restrict__ bcnt,
                                                int E, int W) {
    int i = blockIdx.x * 256 + threadIdx.x;
    int lane = threadIdx.x & 63;
    bool valid = i < E;
    int r = valid ? row[i] : 0;
    int c = valid ? col[i] : 0;
    int w = valid ? r / W : -1;
    ull lt = (1ull << lane) - 1ull;
#pragma unroll
    for (int b = 0; b < NW; ++b) {
        ull m = __ballot(w == b);
        if (m == 0) continue;
        int n = __popcll(m);
        int leader = __ffsll((long long)m) - 1;
        int base = 0;
        if (lane == leader) base = atomicAdd(&bcnt[b], n);
        base = __shfl(base, leader);
        if (w == b) {
            int rk = __popcll(m & lt);
            int p = base + rk;
            if (p < CAP) bkt[(size_t)b * CAP + p] = make_int2(r, c);
        }
    }
}

// ---------------- phase 2: per-(window,slice) LDS histogram ----------------
// 2 rows packed per uint (ushort counts)
__global__ __launch_bounds__(1024) void k_hist2(const int2* __restrict__ bkt,
                                                const int* __restrict__ bcnt,
                                                uint* __restrict__ histU,
                                                int N, int W) {
    __shared__ uint h[6400];
    int bid = blockIdx.x, w = bid & 7, b = bid >> 3;
    int w0 = w * W, WH = W >> 1;
    for (int t = threadIdx.x; t < WH; t += 1024) h[t] = 0;
    __syncthreads();
    int cnt = min(bcnt[w], CAP);
    int e0 = (int)((long long)cnt * b / BSL);
    int e1 = (int)((long long)cnt * (b + 1) / BSL);
    const int2* src = bkt + (size_t)w * CAP;
    for (int i = e0 + threadIdx.x; i < e1; i += 1024) {
        int r = src[i].x - w0;
        atomicAdd(&h[r >> 1], 1u << ((r & 1) << 4));
    }
    __syncthreads();
    uint* dst = histU + (size_t)(w * BSL + b) * WH;
    for (int t = threadIdx.x; t < WH; t += 1024) dst[t] = h[t];
}

// per row-pair: per-slice counts -> per-slice exclusive offsets (in place); deg+dinv
__global__ __launch_bounds__(256) void k_rowsum(uint* __restrict__ histU,
                                                int* __restrict__ deg,
                                                float* __restrict__ dinv,
                                                int N, int W) {
    int q = blockIdx.x * 256 + threadIdx.x;
    int NH = (N + 1) >> 1;
    if (q >= NH) return;
    int r0 = 2 * q;
    int w = r0 / W, WH = W >> 1;
    int qw = (r0 - w * W) >> 1;
    uint run0 = 0, run1 = 0;
    uint* p = histU + (size_t)(w * BSL) * WH + qw;
#pragma unroll 8
    for (int b = 0; b < BSL; ++b) {
        uint v = p[(size_t)b * WH];
        p[(size_t)b * WH] = run0 | (run1 << 16);
        run0 += v & 0xffffu;
        run1 += v >> 16;
    }
    int d0 = (int)run0, d1 = (int)run1;
    deg[r0] = d0;
    dinv[r0] = d0 > 0 ? 1.0f / sqrtf((float)d0) : 0.0f;
    if (r0 + 1 < N) {
        deg[r0 + 1] = d1;
        dinv[r0 + 1] = d1 > 0 ? 1.0f / sqrtf((float)d1) : 0.0f;
    }
}

// start = exclusive prefix of deg (wave-aggregated atomic alloc)
__global__ __launch_bounds__(256) void k_alloc(const int* __restrict__ deg,
                                               int* __restrict__ start,
                                               int* counter, int N) {
    int i = blockIdx.x * 256 + threadIdx.x;
    int lane = threadIdx.x & 63;
    int d = (i < N) ? deg[i] : 0;
    int v = d;
#pragma unroll
    for (int off = 1; off < 64; off <<= 1) {
        int t = __shfl_up(v, off);
        if (lane >= off) v += t;
    }
    int total = __shfl(v, 63);
    int base = 0;
    if (lane == 63) base = atomicAdd(counter, total);
    base = __shfl(base, 63);
    if (i < N) start[i] = base + v - d;
}

// ---------------- phase 3: deterministic scatter into CSR ----------------
// slot = start[r] + slice-offset + LDS cursor; reads only the window's bucket.
__global__ __launch_bounds__(1024) void k_fill3(const int2* __restrict__ bkt,
                                                const int* __restrict__ bcnt,
                                                const int* __restrict__ start,
                                                const uint* __restrict__ histU,
                                                const float* __restrict__ dinv,
                                                int2* __restrict__ ecc,
                                                int N, int W) {
    __shared__ int cur[12800];
    int bid = blockIdx.x, w = bid & 7, b = bid >> 3;
    int w0 = w * W, WH = W >> 1;
    int wlen = min(W, N - w0);
    const uint* hb = histU + (size_t)(w * BSL + b) * WH;
    for (int j = threadIdx.x; 2 * j < wlen; j += 1024) {
        uint off = hb[j];
        int r0 = w0 + 2 * j;
        cur[2 * j] = start[r0] + (int)(off & 0xffffu);
        if (2 * j + 1 < wlen) cur[2 * j + 1] = start[r0 + 1] + (int)(off >> 16);
    }
    __syncthreads();
    int cnt = min(bcnt[w], CAP);
    int e0 = (int)((long long)cnt * b / BSL);
    int e1 = (int)((long long)cnt * (b + 1) / BSL);
    const int2* src = bkt + (size_t)w * CAP;
    for (int i = e0 + threadIdx.x; i < e1; i += 1024) {
        int2 e = src[i];
        int r = e.x - w0;
        int c = e.y;
        int p = atomicAdd(&cur[r], 1);
        int2 pk;
        pk.x = c;
        pk.y = __float_as_int(dinv[c]);
        ecc[p] = pk;
    }
}

// ---------------- layout prep ----------------
__global__ __launch_bounds__(256) void k_pad_x(const float* __restrict__ x,
                                               ushort* __restrict__ xb, int N) {
    int t = blockIdx.x * 256 + threadIdx.x;
    if (t >= N * 64) return;
    int i = t >> 6, c = t & 63;
    float v = (c < 50) ? x[(size_t)i * 50 + c] : 0.f;
    xb[t] = f2bf(v);
}

__global__ __launch_bounds__(256) void k_wt(const float* __restrict__ W1,
                                            const float* __restrict__ W2,
                                            ushort* __restrict__ Wt1,
                                            ushort* __restrict__ Wt2) {
    int t = blockIdx.x * 256 + threadIdx.x;
    if (t >= 2 * 64 * 192) return;
    int half = t / (64 * 192), u = t % (64 * 192);
    int cout = u / 192, k = u % 192;
    int arr = k >> 6, c = k & 63;
    if (half == 0) {
        float v = (c < 50) ? W1[(size_t)(arr * 50 + c) * 50 + cout] : 0.f;
        Wt1[u] = f2bf(v);
    } else {
        float v = (c < 50 && cout < 40) ? W2[(size_t)(arr * 50 + c) * 40 + cout] : 0.f;
        Wt2[u] = f2bf(v);
    }
}

// ---------------- L_hat multiply: one ROW per HALF-WAVE ----------------
// Half-wave h (32 lanes) owns row i entirely: lane c holds channels 2c,2c+1
// (uint). One gather instr = 1 line per half-wave; 8-deep pipeline engages at
// d>=8, so ~16 lines stay in flight per wave for nearly all rows.
__global__ __launch_bounds__(256) void k_lmul(const int* __restrict__ start,
                                              const int* __restrict__ deg,
                                              const int2* __restrict__ ecc,
                                              const float* __restrict__ dinv,
                                              const ushort* __restrict__ v,
                                              const ushort* __restrict__ other,
                                              ushort* __restrict__ out, int N,
                                              float a, float bc) {
    int wid = threadIdx.x >> 6, lane = threadIdx.x & 63;
    int h = lane >> 5, c = lane & 31;
    int i = blockIdx.x * 8 + wid * 2 + h;
    if (i >= N) return;
    int s = start[i];
    int d = deg[i];
    const char* vB = (const char*)v;
    const ull* eccq = (const ull*)ecc;
    float acc0 = 0.f, acc1 = 0.f;
    int k = 0;

    if (d >= 8) {
        ull e[8];
#pragma unroll
        for (int j = 0; j < 8; ++j) e[j] = eccq[s + j];
        for (; k + 16 <= d; k += 8) {
            ull n[8];
#pragma unroll
            for (int j = 0; j < 8; ++j) n[j] = eccq[s + k + 8 + j];
            uint g[8];
#pragma unroll
            for (int j = 0; j < 8; ++j)
                g[j] = *(const uint*)(vB + ((size_t)(uint)e[j] << 7) + (c << 2));
#pragma unroll
            for (int j = 0; j < 8; ++j) {
                float w = __int_as_float((int)(e[j] >> 32));
                acc0 += w * bf2f((ushort)g[j]);
                acc1 += w * bf2f((ushort)(g[j] >> 16));
            }
#pragma unroll
            for (int j = 0; j < 8; ++j) e[j] = n[j];
        }
        {   // drain preloaded block [k, k+8)
            uint g[8];
#pragma unroll
            for (int j = 0; j < 8; ++j)
                g[j] = *(const uint*)(vB + ((size_t)(uint)e[j] << 7) + (c << 2));
#pragma unroll
            for (int j = 0; j < 8; ++j) {
                float w = __int_as_float((int)(e[j] >> 32));
                acc0 += w * bf2f((ushort)g[j]);
                acc1 += w * bf2f((ushort)(g[j] >> 16));
            }
            k += 8;
        }
    }
    for (; k < d; ++k) {
        ull e = eccq[s + k];
        uint g = *(const uint*)(vB + ((size_t)(uint)e << 7) + (c << 2));
        float w = __int_as_float((int)(e >> 32));
        acc0 += w * bf2f((ushort)g);
        acc1 += w * bf2f((ushort)(g >> 16));
    }

    float di = dinv[i];
    float r0 = -a * di * acc0;
    float r1 = -a * di * acc1;
    if (bc != 0.f) {
        uint ov = *(const uint*)((const char*)other + ((size_t)(uint)i << 7) + (c << 2));
        r0 += bc * bf2f((ushort)ov);
        r1 += bc * bf2f((ushort)(ov >> 16));
    }
    uint pk = (uint)f2bf(r0) | ((uint)f2bf(r1) << 16);
    *(uint*)((char*)out + ((size_t)(uint)i << 7) + (c << 2)) = pk;
}

// ---------------- MFMA GEMM: C[N, NCT*16] = [A0|A1|A2] @ Wt^T + b ----------------
template <int NCT, bool RELU, bool BF16OUT>
__global__ __launch_bounds__(256) void k_gemm_mfma(const ushort* __restrict__ A0,
                                                   const ushort* __restrict__ A1,
                                                   const ushort* __restrict__ A2,
                                                   const ushort* __restrict__ Wt,
                                                   const float* __restrict__ bias,
                                                   int biasN,
                                                   ushort* __restrict__ outb,
                                                   float* __restrict__ outf, int N) {
    int lane = threadIdx.x & 63;
    int wv = blockIdx.x * 4 + (threadIdx.x >> 6);
    int nw = gridDim.x * 4;
    int r15 = lane & 15, kq = lane >> 4;

    bf16x8 bfr[6][NCT];
#pragma unroll
    for (int s = 0; s < 6; ++s)
#pragma unroll
        for (int ct = 0; ct < NCT; ++ct)
            bfr[s][ct] = *(const bf16x8*)(Wt + (size_t)(ct * 16 + r15) * 192 + s * 32 + kq * 8);
    float bs[NCT];
#pragma unroll
    for (int ct = 0; ct < NCT; ++ct) {
        int col = ct * 16 + r15;
        bs[ct] = (col < biasN) ? bias[col] : 0.f;
    }

    const ushort* As[3] = {A0, A1, A2};
    int ntile = N >> 4;
    if (wv >= ntile) return;
    bf16x8 af[6];
    {
        int rb = wv << 4;
#pragma unroll
        for (int s = 0; s < 6; ++s)
            af[s] = *(const bf16x8*)(As[s >> 1] + (size_t)(rb + r15) * 64 + (s & 1) * 32 + kq * 8);
    }
    for (int t = wv; t < ntile; t += nw) {
        int tn = t + nw;
        bf16x8 afn[6];
        if (tn < ntile) {
            int rbn = tn << 4;
#pragma unroll
            for (int s = 0; s < 6; ++s)
                afn[s] = *(const bf16x8*)(As[s >> 1] + (size_t)(rbn + r15) * 64 + (s & 1) * 32 + kq * 8);
        }
        f32x4 acc[NCT];
#pragma unroll
        for (int ct = 0; ct < NCT; ++ct) acc[ct] = (f32x4){0.f, 0.f, 0.f, 0.f};
#pragma unroll
        for (int s = 0; s < 6; ++s)
#pragma unroll
            for (int ct = 0; ct < NCT; ++ct)
                acc[ct] = __builtin_amdgcn_mfma_f32_16x16x32_bf16(af[s], bfr[s][ct], acc[ct], 0, 0, 0);
        int rb = t << 4;
#pragma unroll
        for (int ct = 0; ct < NCT; ++ct) {
            int col = ct * 16 + r15;
#pragma unroll
            for (int i = 0; i < 4; ++i) {
                int row = rb + kq * 4 + i;  // C/D: col=lane&15, row=(lane>>4)*4+i  [m89]
                float v = acc[ct][i] + bs[ct];
                if (RELU) v = fmaxf(v, 0.f);
                if (BF16OUT) {
                    outb[(size_t)row * 64 + col] = f2bf(v);
                } else {
                    if (col < 40) outf[(size_t)row * 40 + col] = v;
                }
            }
        }
#pragma unroll
        for (int s = 0; s < 6; ++s) af[s] = afn[s];
    }
}

extern "C" void kernel_launch(void* const* d_in, const int* in_sizes, int n_in,
                              void* d_out, int out_size, void* d_ws, size_t ws_size,
                              hipStream_t stream) {
    const float* x   = (const float*)d_in[0];
    const int*  eidx = (const int*)d_in[1];
    const float* W1  = (const float*)d_in[2];
    const float* b1  = (const float*)d_in[3];
    const float* W2  = (const float*)d_in[4];
    const float* b2  = (const float*)d_in[5];
    float* out = (float*)d_out;

    const int CIN = 50;
    int N = in_sizes[0] / CIN;  // 100000
    int E = in_sizes[1] / 2;    // 1600000
    const int* row = eidx;
    const int* col = eidx + E;

    int W = ((N + NW - 1) / NW + 1) & ~1;  // even window size (12500); must be <= 12800

    char* wsp = (char*)d_ws;
    auto carve = [&](size_t b) -> char* {
        char* p = wsp;
        wsp += (b + 255) & ~(size_t)255;
        return p;
    };
    int*    deg     = (int*)carve((size_t)N * 4);
    int*    startA  = (int*)carve((size_t)N * 4);
    int*    counter = (int*)carve(256);
    int*    bcnt    = (int*)carve(256);
    float*  dinv    = (float*)carve((size_t)N * 4);
    int2*   ecc     = (int2*)carve((size_t)E * 8);
    ushort* xb      = (ushort*)carve((size_t)N * 64 * 2);
    ushort* B1b     = (ushort*)carve((size_t)N * 64 * 2);
    ushort* B2b     = (ushort*)carve((size_t)N * 64 * 2);
    ushort* Hb      = (ushort*)carve((size_t)N * 64 * 2);
    ushort* Wt1     = (ushort*)carve((size_t)64 * 192 * 2);
    ushort* Wt2     = (ushort*)carve((size_t)64 * 192 * 2);
    // aliases (dead before their hosts are written):
    int2* bkt   = (int2*)B1b;  // 8*CAP*8 = 16.8MB spans B1b+B2b; dead after k_fill3
    uint* histU = (uint*)Hb;   // 6.4MB; dead after k_fill3 (Hb written by gemm1)
    (void)ws_size; (void)n_in; (void)out_size;

    hipMemsetAsync(counter, 0, 4, stream);
    hipMemsetAsync(bcnt, 0, NW * 4, stream);

    int gE = (E + 255) / 256;
    int gN = (N + 255) / 256;
    int gW2 = (N + 7) / 8;

    k_bucket<<<gE, 256, 0, stream>>>(row, col, bkt, bcnt, E, W);
    k_hist2<<<NW * BSL, 1024, 0, stream>>>(bkt, bcnt, histU, N, W);
    k_rowsum<<<((N + 1) / 2 + 255) / 256, 256, 0, stream>>>(histU, deg, dinv, N, W);
    k_alloc<<<gN, 256, 0, stream>>>(deg, startA, counter, N);
    k_fill3<<<NW * BSL, 1024, 0, stream>>>(bkt, bcnt, startA, histU, dinv, ecc, N, W);
    k_pad_x<<<(N * 64 + 255) / 256, 256, 0, stream>>>(x, xb, N);
    k_wt<<<(2 * 64 * 192 + 255) / 256, 256, 0, stream>>>(W1, W2, Wt1, Wt2);

    int gG = 392;

    // layer 1
    k_lmul<<<gW2, 256, 0, stream>>>(startA, deg, ecc, dinv, xb, xb, B1b, N, 1.f, 0.f);
    k_lmul<<<gW2, 256, 0, stream>>>(startA, deg, ecc, dinv, B1b, xb, B2b, N, 2.f, -1.f);
    k_gemm_mfma<4, true, true><<<gG, 256, 0, stream>>>(xb, B1b, B2b, Wt1, b1, 50, Hb, nullptr, N);

    // layer 2
    k_lmul<<<gW2, 256, 0, stream>>>(startA, deg, ecc, dinv, Hb, Hb, B1b, N, 1.f, 0.f);
    k_lmul<<<gW2, 256, 0, stream>>>(startA, deg, ecc, dinv, B1b, Hb, B2b, N, 2.f, -1.f);
    k_gemm_mfma<3, false, false><<<gG, 256, 0, stream>>>(Hb, B1b, B2b, Wt2, b2, 40, nullptr, out, N);
}

// Round 10
// 313.896 us; speedup vs baseline: 8.1671x; 8.1671x over previous
//
#include <hip/hip_runtime.h>
#include <hip/hip_bf16.h>
#include <math.h>

typedef short bf16x8 __attribute__((ext_vector_type(8)));
typedef float f32x4 __attribute__((ext_vector_type(4)));
typedef __hip_bfloat16 bf16;
typedef unsigned long long ull;

#define NW 8       // row windows (= XCDs; window w scatter runs on xcd w via bid&7)
#define BSL 32     // slices per window (= CUs per XCD)
#define GP 2048    // partition blocks (must be multiple of 64)

static __device__ __forceinline__ float bf2f(ushort u) {
    unsigned int x = ((unsigned int)u) << 16;
    return __builtin_bit_cast(float, x);
}
static __device__ __forceinline__ ushort f2bf(float f) {
    bf16 h = __float2bfloat16(f);
    return __builtin_bit_cast(ushort, h);
}

// ---------------- CSR build: deterministic two-pass window partition ----------------

// P1: per-block window counts (LDS only)
__global__ __launch_bounds__(256) void k_pcount(const int* __restrict__ row,
                                                uint* __restrict__ counts,
                                                int E, int W) {
    __shared__ uint h[NW];
    if (threadIdx.x < NW) h[threadIdx.x] = 0;
    __syncthreads();
    int blk = blockIdx.x;
    int e0 = (int)((long long)E * blk / GP);
    int e1 = (int)((long long)E * (blk + 1) / GP);
    for (int i = e0 + threadIdx.x; i < e1; i += 256)
        atomicAdd(&h[row[i] / W], 1u);
    __syncthreads();
    if (threadIdx.x < NW) counts[(size_t)blk * NW + threadIdx.x] = h[threadIdx.x];
}

// P2: one block, wave w scans window w's 2048 per-block counts -> exclusive bases
__global__ __launch_bounds__(512) void k_pscan(const uint* __restrict__ counts,
                                               uint* __restrict__ bases,
                                               uint* __restrict__ wtot,
                                               uint* __restrict__ wbase) {
    int wv = threadIdx.x >> 6, lane = threadIdx.x & 63;
    __shared__ uint tot[NW];
    __shared__ uint wb[NW];
    uint v[GP / 64], ex[GP / 64];
#pragma unroll
    for (int t = 0; t < GP / 64; ++t)
        v[t] = counts[(size_t)(t * 64 + lane) * NW + wv];
    uint run = 0;
#pragma unroll
    for (int t = 0; t < GP / 64; ++t) {
        uint s = v[t];
#pragma unroll
        for (int off = 1; off < 64; off <<= 1) {
            uint u = __shfl_up(s, off);
            if (lane >= off) s += u;
        }
        ex[t] = run + s - v[t];
        run += __shfl(s, 63);
    }
    if (lane == 0) tot[wv] = run;
    __syncthreads();
    if (threadIdx.x == 0) {
        uint acc = 0;
        for (int w = 0; w < NW; ++w) {
            wb[w] = acc;
            wbase[w] = acc;
            wtot[w] = tot[w];
            acc += tot[w];
        }
    }
    __syncthreads();
    uint add = wb[wv];
#pragma unroll
    for (int t = 0; t < GP / 64; ++t)
        bases[(size_t)(t * 64 + lane) * NW + wv] = ex[t] + add;
}

// P3: re-read chunk, scatter (r,c) into window-grouped bkt via LDS cursors
__global__ __launch_bounds__(256) void k_pscatter(const int* __restrict__ row,
                                                  const int* __restrict__ col,
                                                  const uint* __restrict__ bases,
                                                  int2* __restrict__ bkt,
                                                  int E, int W) {
    __shared__ uint cur[NW];
    if (threadIdx.x < NW) cur[threadIdx.x] = bases[(size_t)blockIdx.x * NW + threadIdx.x];
    __syncthreads();
    int blk = blockIdx.x;
    int e0 = (int)((long long)E * blk / GP);
    int e1 = (int)((long long)E * (blk + 1) / GP);
    for (int i = e0 + threadIdx.x; i < e1; i += 256) {
        int r = row[i], c = col[i];
        uint p = atomicAdd(&cur[r / W], 1u);
        bkt[p] = make_int2(r, c);
    }
}

// per-(window,slice) LDS histogram over the window's bkt segment
__global__ __launch_bounds__(1024) void k_hist2(const int2* __restrict__ bkt,
                                                const uint* __restrict__ wbase,
                                                const uint* __restrict__ wtot,
                                                uint* __restrict__ histU,
                                                int N, int W) {
    __shared__ uint h[6400];
    int bid = blockIdx.x, w = bid & 7, b = bid >> 3;
    int w0 = w * W, WH = W >> 1;
    for (int t = threadIdx.x; t < WH; t += 1024) h[t] = 0;
    __syncthreads();
    int cnt = (int)wtot[w];
    int e0 = (int)((long long)cnt * b / BSL);
    int e1 = (int)((long long)cnt * (b + 1) / BSL);
    const int2* src = bkt + wbase[w];
    for (int i = e0 + threadIdx.x; i < e1; i += 1024) {
        int r = src[i].x - w0;
        atomicAdd(&h[r >> 1], 1u << ((r & 1) << 4));
    }
    __syncthreads();
    uint* dst = histU + (size_t)(w * BSL + b) * WH;
    for (int t = threadIdx.x; t < WH; t += 1024) dst[t] = h[t];
}

// per row-pair: per-slice counts -> per-slice exclusive offsets (in place); deg+dinv
__global__ __launch_bounds__(256) void k_rowsum(uint* __restrict__ histU,
                                                int* __restrict__ deg,
                                                float* __restrict__ dinv,
                                                int N, int W) {
    int q = blockIdx.x * 256 + threadIdx.x;
    int NH = (N + 1) >> 1;
    if (q >= NH) return;
    int r0 = 2 * q;
    int w = r0 / W, WH = W >> 1;
    int qw = (r0 - w * W) >> 1;
    uint run0 = 0, run1 = 0;
    uint* p = histU + (size_t)(w * BSL) * WH + qw;
#pragma unroll 8
    for (int b = 0; b < BSL; ++b) {
        uint v = p[(size_t)b * WH];
        p[(size_t)b * WH] = run0 | (run1 << 16);
        run0 += v & 0xffffu;
        run1 += v >> 16;
    }
    int d0 = (int)run0, d1 = (int)run1;
    deg[r0] = d0;
    dinv[r0] = d0 > 0 ? 1.0f / sqrtf((float)d0) : 0.0f;
    if (r0 + 1 < N) {
        deg[r0 + 1] = d1;
        dinv[r0 + 1] = d1 > 0 ? 1.0f / sqrtf((float)d1) : 0.0f;
    }
}

// start = exclusive prefix of deg (wave-aggregated atomic alloc)
__global__ __launch_bounds__(256) void k_alloc(const int* __restrict__ deg,
                                               int* __restrict__ start,
                                               int* counter, int N) {
    int i = blockIdx.x * 256 + threadIdx.x;
    int lane = threadIdx.x & 63;
    int d = (i < N) ? deg[i] : 0;
    int v = d;
#pragma unroll
    for (int off = 1; off < 64; off <<= 1) {
        int t = __shfl_up(v, off);
        if (lane >= off) v += t;
    }
    int total = __shfl(v, 63);
    int base = 0;
    if (lane == 63) base = atomicAdd(counter, total);
    base = __shfl(base, 63);
    if (i < N) start[i] = base + v - d;
}

// deterministic scatter into CSR; reads only the window's bkt segment
__global__ __launch_bounds__(1024) void k_fill3(const int2* __restrict__ bkt,
                                                const uint* __restrict__ wbase,
                                                const uint* __restrict__ wtot,
                                                const int* __restrict__ start,
                                                const uint* __restrict__ histU,
                                                const float* __restrict__ dinv,
                                                int2* __restrict__ ecc,
                                                int N, int W) {
    __shared__ int cur[12800];
    int bid = blockIdx.x, w = bid & 7, b = bid >> 3;
    int w0 = w * W, WH = W >> 1;
    int wlen = min(W, N - w0);
    const uint* hb = histU + (size_t)(w * BSL + b) * WH;
    for (int j = threadIdx.x; 2 * j < wlen; j += 1024) {
        uint off = hb[j];
        int r0 = w0 + 2 * j;
        cur[2 * j] = start[r0] + (int)(off & 0xffffu);
        if (2 * j + 1 < wlen) cur[2 * j + 1] = start[r0 + 1] + (int)(off >> 16);
    }
    __syncthreads();
    int cnt = (int)wtot[w];
    int e0 = (int)((long long)cnt * b / BSL);
    int e1 = (int)((long long)cnt * (b + 1) / BSL);
    const int2* src = bkt + wbase[w];
    for (int i = e0 + threadIdx.x; i < e1; i += 1024) {
        int2 e = src[i];
        int r = e.x - w0;
        int c = e.y;
        int p = atomicAdd(&cur[r], 1);
        int2 pk;
        pk.x = c;
        pk.y = __float_as_int(dinv[c]);
        ecc[p] = pk;
    }
}

// ---------------- layout prep ----------------
__global__ __launch_bounds__(256) void k_pad_x(const float* __restrict__ x,
                                               ushort* __restrict__ xb, int N) {
    int t = blockIdx.x * 256 + threadIdx.x;
    if (t >= N * 64) return;
    int i = t >> 6, c = t & 63;
    float v = (c < 50) ? x[(size_t)i * 50 + c] : 0.f;
    xb[t] = f2bf(v);
}

__global__ __launch_bounds__(256) void k_wt(const float* __restrict__ W1,
                                            const float* __restrict__ W2,
                                            ushort* __restrict__ Wt1,
                                            ushort* __restrict__ Wt2) {
    int t = blockIdx.x * 256 + threadIdx.x;
    if (t >= 2 * 64 * 192) return;
    int half = t / (64 * 192), u = t % (64 * 192);
    int cout = u / 192, k = u % 192;
    int arr = k >> 6, c = k & 63;
    if (half == 0) {
        float v = (c < 50) ? W1[(size_t)(arr * 50 + c) * 50 + cout] : 0.f;
        Wt1[u] = f2bf(v);
    } else {
        float v = (c < 50 && cout < 40) ? W2[(size_t)(arr * 50 + c) * 40 + cout] : 0.f;
        Wt2[u] = f2bf(v);
    }
}

// ---------------- L_hat multiply: one ROW per HALF-WAVE ----------------
__global__ __launch_bounds__(256) void k_lmul(const int* __restrict__ start,
                                              const int* __restrict__ deg,
                                              const int2* __restrict__ ecc,
                                              const float* __restrict__ dinv,
                                              const ushort* __restrict__ v,
                                              const ushort* __restrict__ other,
                                              ushort* __restrict__ out, int N,
                                              float a, float bc) {
    int wid = threadIdx.x >> 6, lane = threadIdx.x & 63;
    int h = lane >> 5, c = lane & 31;
    int i = blockIdx.x * 8 + wid * 2 + h;
    if (i >= N) return;
    int s = start[i];
    int d = deg[i];
    const char* vB = (const char*)v;
    const ull* eccq = (const ull*)ecc;
    float acc0 = 0.f, acc1 = 0.f;
    int k = 0;

    if (d >= 8) {
        ull e[8];
#pragma unroll
        for (int j = 0; j < 8; ++j) e[j] = eccq[s + j];
        for (; k + 16 <= d; k += 8) {
            ull n[8];
#pragma unroll
            for (int j = 0; j < 8; ++j) n[j] = eccq[s + k + 8 + j];
            uint g[8];
#pragma unroll
            for (int j = 0; j < 8; ++j)
                g[j] = *(const uint*)(vB + ((size_t)(uint)e[j] << 7) + (c << 2));
#pragma unroll
            for (int j = 0; j < 8; ++j) {
                float w = __int_as_float((int)(e[j] >> 32));
                acc0 += w * bf2f((ushort)g[j]);
                acc1 += w * bf2f((ushort)(g[j] >> 16));
            }
#pragma unroll
            for (int j = 0; j < 8; ++j) e[j] = n[j];
        }
        {
            uint g[8];
#pragma unroll
            for (int j = 0; j < 8; ++j)
                g[j] = *(const uint*)(vB + ((size_t)(uint)e[j] << 7) + (c << 2));
#pragma unroll
            for (int j = 0; j < 8; ++j) {
                float w = __int_as_float((int)(e[j] >> 32));
                acc0 += w * bf2f((ushort)g[j]);
                acc1 += w * bf2f((ushort)(g[j] >> 16));
            }
            k += 8;
        }
    }
    for (; k < d; ++k) {
        ull e = eccq[s + k];
        uint g = *(const uint*)(vB + ((size_t)(uint)e << 7) + (c << 2));
        float w = __int_as_float((int)(e >> 32));
        acc0 += w * bf2f((ushort)g);
        acc1 += w * bf2f((ushort)(g >> 16));
    }

    float di = dinv[i];
    float r0 = -a * di * acc0;
    float r1 = -a * di * acc1;
    if (bc != 0.f) {
        uint ov = *(const uint*)((const char*)other + ((size_t)(uint)i << 7) + (c << 2));
        r0 += bc * bf2f((ushort)ov);
        r1 += bc * bf2f((ushort)(ov >> 16));
    }
    uint pk = (uint)f2bf(r0) | ((uint)f2bf(r1) << 16);
    *(uint*)((char*)out + ((size_t)(uint)i << 7) + (c << 2)) = pk;
}

// ---------------- MFMA GEMM: C[N, NCT*16] = [A0|A1|A2] @ Wt^T + b ----------------
template <int NCT, bool RELU, bool BF16OUT>
__global__ __launch_bounds__(256) void k_gemm_mfma(const ushort* __restrict__ A0,
                                                   const ushort* __restrict__ A1,
                                                   const ushort* __restrict__ A2,
                                                   const ushort* __restrict__ Wt,
                                                   const float* __restrict__ bias,
                                                   int biasN,
                                                   ushort* __restrict__ outb,
                                                   float* __restrict__ outf, int N) {
    int lane = threadIdx.x & 63;
    int wv = blockIdx.x * 4 + (threadIdx.x >> 6);
    int nw = gridDim.x * 4;
    int r15 = lane & 15, kq = lane >> 4;

    bf16x8 bfr[6][NCT];
#pragma unroll
    for (int s = 0; s < 6; ++s)
#pragma unroll
        for (int ct = 0; ct < NCT; ++ct)
            bfr[s][ct] = *(const bf16x8*)(Wt + (size_t)(ct * 16 + r15) * 192 + s * 32 + kq * 8);
    float bs[NCT];
#pragma unroll
    for (int ct = 0; ct < NCT; ++ct) {
        int col = ct * 16 + r15;
        bs[ct] = (col < biasN) ? bias[col] : 0.f;
    }

    const ushort* As[3] = {A0, A1, A2};
    int ntile = N >> 4;
    if (wv >= ntile) return;
    bf16x8 af[6];
    {
        int rb = wv << 4;
#pragma unroll
        for (int s = 0; s < 6; ++s)
            af[s] = *(const bf16x8*)(As[s >> 1] + (size_t)(rb + r15) * 64 + (s & 1) * 32 + kq * 8);
    }
    for (int t = wv; t < ntile; t += nw) {
        int tn = t + nw;
        bf16x8 afn[6];
        if (tn < ntile) {
            int rbn = tn << 4;
#pragma unroll
            for (int s = 0; s < 6; ++s)
                afn[s] = *(const bf16x8*)(As[s >> 1] + (size_t)(rbn + r15) * 64 + (s & 1) * 32 + kq * 8);
        }
        f32x4 acc[NCT];
#pragma unroll
        for (int ct = 0; ct < NCT; ++ct) acc[ct] = (f32x4){0.f, 0.f, 0.f, 0.f};
#pragma unroll
        for (int s = 0; s < 6; ++s)
#pragma unroll
            for (int ct = 0; ct < NCT; ++ct)
                acc[ct] = __builtin_amdgcn_mfma_f32_16x16x32_bf16(af[s], bfr[s][ct], acc[ct], 0, 0, 0);
        int rb = t << 4;
#pragma unroll
        for (int ct = 0; ct < NCT; ++ct) {
            int col = ct * 16 + r15;
#pragma unroll
            for (int i = 0; i < 4; ++i) {
                int row = rb + kq * 4 + i;  // C/D: col=lane&15, row=(lane>>4)*4+i  [m89]
                float v = acc[ct][i] + bs[ct];
                if (RELU) v = fmaxf(v, 0.f);
                if (BF16OUT) {
                    outb[(size_t)row * 64 + col] = f2bf(v);
                } else {
                    if (col < 40) outf[(size_t)row * 40 + col] = v;
                }
            }
        }
#pragma unroll
        for (int s = 0; s < 6; ++s) af[s] = afn[s];
    }
}

extern "C" void kernel_launch(void* const* d_in, const int* in_sizes, int n_in,
                              void* d_out, int out_size, void* d_ws, size_t ws_size,
                              hipStream_t stream) {
    const float* x   = (const float*)d_in[0];
    const int*  eidx = (const int*)d_in[1];
    const float* W1  = (const float*)d_in[2];
    const float* b1  = (const float*)d_in[3];
    const float* W2  = (const float*)d_in[4];
    const float* b2  = (const float*)d_in[5];
    float* out = (float*)d_out;

    const int CIN = 50;
    int N = in_sizes[0] / CIN;  // 100000
    int E = in_sizes[1] / 2;    // 1600000
    const int* row = eidx;
    const int* col = eidx + E;

    int W = ((N + NW - 1) / NW + 1) & ~1;  // even window size (12500); must be <= 12800

    char* wsp = (char*)d_ws;
    auto carve = [&](size_t b) -> char* {
        char* p = wsp;
        wsp += (b + 255) & ~(size_t)255;
        return p;
    };
    int*    deg     = (int*)carve((size_t)N * 4);
    int*    startA  = (int*)carve((size_t)N * 4);
    int*    counter = (int*)carve(256);
    uint*   wtot    = (uint*)carve(256);
    uint*   wbase   = (uint*)carve(256);
    uint*   counts  = (uint*)carve((size_t)GP * NW * 4);
    uint*   bases   = (uint*)carve((size_t)GP * NW * 4);
    float*  dinv    = (float*)carve((size_t)N * 4);
    int2*   ecc     = (int2*)carve((size_t)E * 8);
    ushort* xb      = (ushort*)carve((size_t)N * 64 * 2);
    ushort* B1b     = (ushort*)carve((size_t)N * 64 * 2);
    ushort* B2b     = (ushort*)carve((size_t)N * 64 * 2);
    ushort* Hb      = (ushort*)carve((size_t)N * 64 * 2);
    ushort* Wt1     = (ushort*)carve((size_t)64 * 192 * 2);
    ushort* Wt2     = (ushort*)carve((size_t)64 * 192 * 2);
    // aliases (dead before their hosts are written):
    int2* bkt   = (int2*)B1b;  // E*8 = 12.8MB = N*128B; consumed by k_fill3 before lmul-1
    uint* histU = (uint*)Hb;   // 6.4MB; consumed by k_fill3 before gemm1 writes Hb
    (void)ws_size; (void)n_in; (void)out_size;

    hipMemsetAsync(counter, 0, 4, stream);

    int gN = (N + 255) / 256;
    int gW2 = (N + 7) / 8;

    k_pcount<<<GP, 256, 0, stream>>>(row, counts, E, W);
    k_pscan<<<1, 512, 0, stream>>>(counts, bases, wtot, wbase);
    k_pscatter<<<GP, 256, 0, stream>>>(row, col, bases, bkt, E, W);
    k_hist2<<<NW * BSL, 1024, 0, stream>>>(bkt, wbase, wtot, histU, N, W);
    k_rowsum<<<((N + 1) / 2 + 255) / 256, 256, 0, stream>>>(histU, deg, dinv, N, W);
    k_alloc<<<gN, 256, 0, stream>>>(deg, startA, counter, N);
    k_fill3<<<NW * BSL, 1024, 0, stream>>>(bkt, wbase, wtot, startA, histU, dinv, ecc, N, W);
    k_pad_x<<<(N * 64 + 255) / 256, 256, 0, stream>>>(x, xb, N);
    k_wt<<<(2 * 64 * 192 + 255) / 256, 256, 0, stream>>>(W1, W2, Wt1, Wt2);

    int gG = 392;

    // layer 1
    k_lmul<<<gW2, 256, 0, stream>>>(startA, deg, ecc, dinv, xb, xb, B1b, N, 1.f, 0.f);
    k_lmul<<<gW2, 256, 0, stream>>>(startA, deg, ecc, dinv, B1b, xb, B2b, N, 2.f, -1.f);
    k_gemm_mfma<4, true, true><<<gG, 256, 0, stream>>>(xb, B1b, B2b, Wt1, b1, 50, Hb, nullptr, N);

    // layer 2
    k_lmul<<<gW2, 256, 0, stream>>>(startA, deg, ecc, dinv, Hb, Hb, B1b, N, 1.f, 0.f);
    k_lmul<<<gW2, 256, 0, stream>>>(startA, deg, ecc, dinv, B1b, Hb, B2b, N, 2.f, -1.f);
    k_gemm_mfma<3, false, false><<<gG, 256, 0, stream>>>(Hb, B1b, B2b, Wt2, b2, 40, nullptr, out, N);
}

// Round 11
// 283.849 us; speedup vs baseline: 9.0317x; 1.1059x over previous
//
#include <hip/hip_runtime.h>
#include <hip/hip_bf16.h>
#include <math.h>

typedef short bf16x8 __attribute__((ext_vector_type(8)));
typedef float f32x4 __attribute__((ext_vector_type(4)));
typedef __hip_bfloat16 bf16;
typedef unsigned long long ull;

#define NW 8       // row windows (= XCDs; window w scatter runs on xcd w via bid&7)
#define BSL 32     // slices per window (= CUs per XCD)
#define GP 2048    // partition blocks (must be multiple of 64)
#define WTB 96     // weight-transpose blocks (2*64*192/256)

static __device__ __forceinline__ float bf2f(ushort u) {
    unsigned int x = ((unsigned int)u) << 16;
    return __builtin_bit_cast(float, x);
}
static __device__ __forceinline__ ushort f2bf(float f) {
    bf16 h = __float2bfloat16(f);
    return __builtin_bit_cast(ushort, h);
}

// ---------------- prep: pcount + weight transpose + x pad, one launch ----------------
__global__ __launch_bounds__(256) void k_prep(const int* __restrict__ row,
                                              const float* __restrict__ x,
                                              const float* __restrict__ W1,
                                              const float* __restrict__ W2,
                                              uint* __restrict__ counts,
                                              ushort* __restrict__ xb,
                                              ushort* __restrict__ Wt1,
                                              ushort* __restrict__ Wt2,
                                              int E, int N, int W) {
    int bid = blockIdx.x;
    if (bid < GP) {  // per-block window counts (LDS only)
        __shared__ uint h[NW];
        if (threadIdx.x < NW) h[threadIdx.x] = 0;
        __syncthreads();
        int e0 = (int)((long long)E * bid / GP);
        int e1 = (int)((long long)E * (bid + 1) / GP);
        for (int i = e0 + threadIdx.x; i < e1; i += 256)
            atomicAdd(&h[row[i] / W], 1u);
        __syncthreads();
        if (threadIdx.x < NW) counts[(size_t)bid * NW + threadIdx.x] = h[threadIdx.x];
        return;
    }
    if (bid < GP + WTB) {  // Wt[cout][arr*64+c], bf16, zero-padded
        int t = (bid - GP) * 256 + threadIdx.x;  // < 24576
        int half = t / (64 * 192), u = t % (64 * 192);
        int cout = u / 192, k = u % 192;
        int arr = k >> 6, c = k & 63;
        if (half == 0) {
            float v = (c < 50) ? W1[(size_t)(arr * 50 + c) * 50 + cout] : 0.f;
            Wt1[u] = f2bf(v);
        } else {
            float v = (c < 50 && cout < 40) ? W2[(size_t)(arr * 50 + c) * 40 + cout] : 0.f;
            Wt2[u] = f2bf(v);
        }
        return;
    }
    // pad x: f32 [N][50] -> bf16 [N][64]; 2 channels per thread (uint store)
    int idx = (bid - GP - WTB) * 256 + threadIdx.x;
    if (idx >= N * 32) return;
    int i = idx >> 5, sl = idx & 31;
    uint pk = 0;
    if (sl < 25) {
        float2 f = *(const float2*)(x + (size_t)i * 50 + sl * 2);
        pk = (uint)f2bf(f.x) | ((uint)f2bf(f.y) << 16);
    }
    ((uint*)xb)[idx] = pk;
}

// P2: one block, wave w scans window w's per-block counts -> exclusive bases
__global__ __launch_bounds__(512) void k_pscan(const uint* __restrict__ counts,
                                               uint* __restrict__ bases,
                                               uint* __restrict__ wtot,
                                               uint* __restrict__ wbase,
                                               int* __restrict__ counter) {
    if (threadIdx.x == 0) *counter = 0;  // zeroed for k_rowsum2 (replaces memset)
    int wv = threadIdx.x >> 6, lane = threadIdx.x & 63;
    __shared__ uint tot[NW];
    __shared__ uint wb[NW];
    uint v[GP / 64], ex[GP / 64];
#pragma unroll
    for (int t = 0; t < GP / 64; ++t)
        v[t] = counts[(size_t)(t * 64 + lane) * NW + wv];
    uint run = 0;
#pragma unroll
    for (int t = 0; t < GP / 64; ++t) {
        uint s = v[t];
#pragma unroll
        for (int off = 1; off < 64; off <<= 1) {
            uint u = __shfl_up(s, off);
            if (lane >= off) s += u;
        }
        ex[t] = run + s - v[t];
        run += __shfl(s, 63);
    }
    if (lane == 0) tot[wv] = run;
    __syncthreads();
    if (threadIdx.x == 0) {
        uint acc = 0;
        for (int w = 0; w < NW; ++w) {
            wb[w] = acc;
            wbase[w] = acc;
            wtot[w] = tot[w];
            acc += tot[w];
        }
    }
    __syncthreads();
    uint add = wb[wv];
#pragma unroll
    for (int t = 0; t < GP / 64; ++t)
        bases[(size_t)(t * 64 + lane) * NW + wv] = ex[t] + add;
}

// P3: re-read chunk, scatter (r,c) into window-grouped bkt via LDS cursors
__global__ __launch_bounds__(256) void k_pscatter(const int* __restrict__ row,
                                                  const int* __restrict__ col,
                                                  const uint* __restrict__ bases,
                                                  int2* __restrict__ bkt,
                                                  int E, int W) {
    __shared__ uint cur[NW];
    if (threadIdx.x < NW) cur[threadIdx.x] = bases[(size_t)blockIdx.x * NW + threadIdx.x];
    __syncthreads();
    int blk = blockIdx.x;
    int e0 = (int)((long long)E * blk / GP);
    int e1 = (int)((long long)E * (blk + 1) / GP);
    for (int i = e0 + threadIdx.x; i < e1; i += 256) {
        int r = row[i], c = col[i];
        uint p = atomicAdd(&cur[r / W], 1u);
        bkt[p] = make_int2(r, c);
    }
}

// per-(window,slice) LDS histogram over the window's bkt segment
__global__ __launch_bounds__(1024) void k_hist2(const int2* __restrict__ bkt,
                                                const uint* __restrict__ wbase,
                                                const uint* __restrict__ wtot,
                                                uint* __restrict__ histU,
                                                int N, int W) {
    __shared__ uint h[6400];
    int bid = blockIdx.x, w = bid & 7, b = bid >> 3;
    int w0 = w * W, WH = W >> 1;
    for (int t = threadIdx.x; t < WH; t += 1024) h[t] = 0;
    __syncthreads();
    int cnt = (int)wtot[w];
    int e0 = (int)((long long)cnt * b / BSL);
    int e1 = (int)((long long)cnt * (b + 1) / BSL);
    const int2* src = bkt + wbase[w];
    for (int i = e0 + threadIdx.x; i < e1; i += 1024) {
        int r = src[i].x - w0;
        atomicAdd(&h[r >> 1], 1u << ((r & 1) << 4));
    }
    __syncthreads();
    uint* dst = histU + (size_t)(w * BSL + b) * WH;
    for (int t = threadIdx.x; t < WH; t += 1024) dst[t] = h[t];
}

// rowsum + alloc fused: per-slice offsets in place, deg/dinv, and start via
// block scan + one global atomic per block (block order permutes start ranges,
// which is harmless: ranges stay disjoint and per-row edge order is unchanged)
__global__ __launch_bounds__(256) void k_rowsum2(uint* __restrict__ histU,
                                                 int* __restrict__ deg,
                                                 float* __restrict__ dinv,
                                                 int* __restrict__ start,
                                                 int* __restrict__ counter,
                                                 int N, int W) {
    int q = blockIdx.x * 256 + threadIdx.x;
    int NH = (N + 1) >> 1;
    int lane = threadIdx.x & 63, wv = threadIdx.x >> 6;
    uint run0 = 0, run1 = 0;
    int r0 = 2 * q;
    if (q < NH) {
        int w = r0 / W, WH = W >> 1;
        int qw = (r0 - w * W) >> 1;
        uint* p = histU + (size_t)(w * BSL) * WH + qw;
#pragma unroll 8
        for (int b = 0; b < BSL; ++b) {
            uint v = p[(size_t)b * WH];
            p[(size_t)b * WH] = run0 | (run1 << 16);
            run0 += v & 0xffffu;
            run1 += v >> 16;
        }
        int d0 = (int)run0, d1 = (int)run1;
        deg[r0] = d0;
        dinv[r0] = d0 > 0 ? 1.0f / sqrtf((float)d0) : 0.0f;
        if (r0 + 1 < N) {
            deg[r0 + 1] = d1;
            dinv[r0 + 1] = d1 > 0 ? 1.0f / sqrtf((float)d1) : 0.0f;
        }
    }
    int t = (q < NH) ? (int)(run0 + run1) : 0;
    int s = t;
#pragma unroll
    for (int off = 1; off < 64; off <<= 1) {
        int u = __shfl_up(s, off);
        if (lane >= off) s += u;
    }
    __shared__ int wsum[4];
    if (lane == 63) wsum[wv] = s;
    __syncthreads();
    if (threadIdx.x == 0) {
        int a0 = wsum[0], a1 = wsum[1], a2 = wsum[2], a3 = wsum[3];
        int bb = atomicAdd(counter, a0 + a1 + a2 + a3);
        wsum[0] = bb;
        wsum[1] = bb + a0;
        wsum[2] = bb + a0 + a1;
        wsum[3] = bb + a0 + a1 + a2;
    }
    __syncthreads();
    int ex = wsum[wv] + (s - t);
    if (q < NH) {
        start[r0] = ex;
        if (r0 + 1 < N) start[r0 + 1] = ex + (int)run0;
    }
}

// deterministic scatter into CSR; reads only the window's bkt segment
__global__ __launch_bounds__(1024) void k_fill3(const int2* __restrict__ bkt,
                                                const uint* __restrict__ wbase,
                                                const uint* __restrict__ wtot,
                                                const int* __restrict__ start,
                                                const uint* __restrict__ histU,
                                                const float* __restrict__ dinv,
                                                int2* __restrict__ ecc,
                                                int N, int W) {
    __shared__ int cur[12800];
    int bid = blockIdx.x, w = bid & 7, b = bid >> 3;
    int w0 = w * W, WH = W >> 1;
    int wlen = min(W, N - w0);
    const uint* hb = histU + (size_t)(w * BSL + b) * WH;
    for (int j = threadIdx.x; 2 * j < wlen; j += 1024) {
        uint off = hb[j];
        int r0 = w0 + 2 * j;
        cur[2 * j] = start[r0] + (int)(off & 0xffffu);
        if (2 * j + 1 < wlen) cur[2 * j + 1] = start[r0 + 1] + (int)(off >> 16);
    }
    __syncthreads();
    int cnt = (int)wtot[w];
    int e0 = (int)((long long)cnt * b / BSL);
    int e1 = (int)((long long)cnt * (b + 1) / BSL);
    const int2* src = bkt + wbase[w];
    for (int i = e0 + threadIdx.x; i < e1; i += 1024) {
        int2 e = src[i];
        int r = e.x - w0;
        int c = e.y;
        int p = atomicAdd(&cur[r], 1);
        int2 pk;
        pk.x = c;
        pk.y = __float_as_int(dinv[c]);
        ecc[p] = pk;
    }
}

// ---------------- L_hat multiply: one ROW per HALF-WAVE (at L2-fill wall) ----------------
__global__ __launch_bounds__(256) void k_lmul(const int* __restrict__ start,
                                              const int* __restrict__ deg,
                                              const int2* __restrict__ ecc,
                                              const float* __restrict__ dinv,
                                              const ushort* __restrict__ v,
                                              const ushort* __restrict__ other,
                                              ushort* __restrict__ out, int N,
                                              float a, float bc) {
    int wid = threadIdx.x >> 6, lane = threadIdx.x & 63;
    int h = lane >> 5, c = lane & 31;
    int i = blockIdx.x * 8 + wid * 2 + h;
    if (i >= N) return;
    int s = start[i];
    int d = deg[i];
    const char* vB = (const char*)v;
    const ull* eccq = (const ull*)ecc;
    float acc0 = 0.f, acc1 = 0.f;
    int k = 0;

    if (d >= 8) {
        ull e[8];
#pragma unroll
        for (int j = 0; j < 8; ++j) e[j] = eccq[s + j];
        for (; k + 16 <= d; k += 8) {
            ull n[8];
#pragma unroll
            for (int j = 0; j < 8; ++j) n[j] = eccq[s + k + 8 + j];
            uint g[8];
#pragma unroll
            for (int j = 0; j < 8; ++j)
                g[j] = *(const uint*)(vB + ((size_t)(uint)e[j] << 7) + (c << 2));
#pragma unroll
            for (int j = 0; j < 8; ++j) {
                float w = __int_as_float((int)(e[j] >> 32));
                acc0 += w * bf2f((ushort)g[j]);
                acc1 += w * bf2f((ushort)(g[j] >> 16));
            }
#pragma unroll
            for (int j = 0; j < 8; ++j) e[j] = n[j];
        }
        {
            uint g[8];
#pragma unroll
            for (int j = 0; j < 8; ++j)
                g[j] = *(const uint*)(vB + ((size_t)(uint)e[j] << 7) + (c << 2));
#pragma unroll
            for (int j = 0; j < 8; ++j) {
                float w = __int_as_float((int)(e[j] >> 32));
                acc0 += w * bf2f((ushort)g[j]);
                acc1 += w * bf2f((ushort)(g[j] >> 16));
            }
            k += 8;
        }
    }
    for (; k < d; ++k) {
        ull e = eccq[s + k];
        uint g = *(const uint*)(vB + ((size_t)(uint)e << 7) + (c << 2));
        float w = __int_as_float((int)(e >> 32));
        acc0 += w * bf2f((ushort)g);
        acc1 += w * bf2f((ushort)(g >> 16));
    }

    float di = dinv[i];
    float r0 = -a * di * acc0;
    float r1 = -a * di * acc1;
    if (bc != 0.f) {
        uint ov = *(const uint*)((const char*)other + ((size_t)(uint)i << 7) + (c << 2));
        r0 += bc * bf2f((ushort)ov);
        r1 += bc * bf2f((ushort)(ov >> 16));
    }
    uint pk = (uint)f2bf(r0) | ((uint)f2bf(r1) << 16);
    *(uint*)((char*)out + ((size_t)(uint)i << 7) + (c << 2)) = pk;
}

// ---------------- MFMA GEMM: C[N, NCT*16] = [A0|A1|A2] @ Wt^T + b ----------------
template <int NCT, bool RELU, bool BF16OUT>
__global__ __launch_bounds__(256) void k_gemm_mfma(const ushort* __restrict__ A0,
                                                   const ushort* __restrict__ A1,
                                                   const ushort* __restrict__ A2,
                                                   const ushort* __restrict__ Wt,
                                                   const float* __restrict__ bias,
                                                   int biasN,
                                                   ushort* __restrict__ outb,
                                                   float* __restrict__ outf, int N) {
    int lane = threadIdx.x & 63;
    int wv = blockIdx.x * 4 + (threadIdx.x >> 6);
    int nw = gridDim.x * 4;
    int r15 = lane & 15, kq = lane >> 4;

    bf16x8 bfr[6][NCT];
#pragma unroll
    for (int s = 0; s < 6; ++s)
#pragma unroll
        for (int ct = 0; ct < NCT; ++ct)
            bfr[s][ct] = *(const bf16x8*)(Wt + (size_t)(ct * 16 + r15) * 192 + s * 32 + kq * 8);
    float bs[NCT];
#pragma unroll
    for (int ct = 0; ct < NCT; ++ct) {
        int col = ct * 16 + r15;
        bs[ct] = (col < biasN) ? bias[col] : 0.f;
    }

    const ushort* As[3] = {A0, A1, A2};
    int ntile = N >> 4;
    if (wv >= ntile) return;
    bf16x8 af[6];
    {
        int rb = wv << 4;
#pragma unroll
        for (int s = 0; s < 6; ++s)
            af[s] = *(const bf16x8*)(As[s >> 1] + (size_t)(rb + r15) * 64 + (s & 1) * 32 + kq * 8);
    }
    for (int t = wv; t < ntile; t += nw) {
        int tn = t + nw;
        bf16x8 afn[6];
        if (tn < ntile) {
            int rbn = tn << 4;
#pragma unroll
            for (int s = 0; s < 6; ++s)
                afn[s] = *(const bf16x8*)(As[s >> 1] + (size_t)(rbn + r15) * 64 + (s & 1) * 32 + kq * 8);
        }
        f32x4 acc[NCT];
#pragma unroll
        for (int ct = 0; ct < NCT; ++ct) acc[ct] = (f32x4){0.f, 0.f, 0.f, 0.f};
#pragma unroll
        for (int s = 0; s < 6; ++s)
#pragma unroll
            for (int ct = 0; ct < NCT; ++ct)
                acc[ct] = __builtin_amdgcn_mfma_f32_16x16x32_bf16(af[s], bfr[s][ct], acc[ct], 0, 0, 0);
        int rb = t << 4;
#pragma unroll
        for (int ct = 0; ct < NCT; ++ct) {
            int col = ct * 16 + r15;
#pragma unroll
            for (int i = 0; i < 4; ++i) {
                int row = rb + kq * 4 + i;  // C/D: col=lane&15, row=(lane>>4)*4+i  [m89]
                float v = acc[ct][i] + bs[ct];
                if (RELU) v = fmaxf(v, 0.f);
                if (BF16OUT) {
                    outb[(size_t)row * 64 + col] = f2bf(v);
                } else {
                    if (col < 40) outf[(size_t)row * 40 + col] = v;
                }
            }
        }
#pragma unroll
        for (int s = 0; s < 6; ++s) af[s] = afn[s];
    }
}

extern "C" void kernel_launch(void* const* d_in, const int* in_sizes, int n_in,
                              void* d_out, int out_size, void* d_ws, size_t ws_size,
                              hipStream_t stream) {
    const float* x   = (const float*)d_in[0];
    const int*  eidx = (const int*)d_in[1];
    const float* W1  = (const float*)d_in[2];
    const float* b1  = (const float*)d_in[3];
    const float* W2  = (const float*)d_in[4];
    const float* b2  = (const float*)d_in[5];
    float* out = (float*)d_out;

    const int CIN = 50;
    int N = in_sizes[0] / CIN;  // 100000
    int E = in_sizes[1] / 2;    // 1600000
    const int* row = eidx;
    const int* col = eidx + E;

    int W = ((N + NW - 1) / NW + 1) & ~1;  // even window size (12500); must be <= 12800

    char* wsp = (char*)d_ws;
    auto carve = [&](size_t b) -> char* {
        char* p = wsp;
        wsp += (b + 255) & ~(size_t)255;
        return p;
    };
    int*    deg     = (int*)carve((size_t)N * 4);
    int*    startA  = (int*)carve((size_t)N * 4);
    int*    counter = (int*)carve(256);
    uint*   wtot    = (uint*)carve(256);
    uint*   wbase   = (uint*)carve(256);
    uint*   counts  = (uint*)carve((size_t)GP * NW * 4);
    uint*   bases   = (uint*)carve((size_t)GP * NW * 4);
    float*  dinv    = (float*)carve((size_t)N * 4);
    int2*   ecc     = (int2*)carve((size_t)E * 8);
    ushort* xb      = (ushort*)carve((size_t)N * 64 * 2);
    ushort* B1b     = (ushort*)carve((size_t)N * 64 * 2);
    ushort* B2b     = (ushort*)carve((size_t)N * 64 * 2);
    ushort* Hb      = (ushort*)carve((size_t)N * 64 * 2);
    ushort* Wt1     = (ushort*)carve((size_t)64 * 192 * 2);
    ushort* Wt2     = (ushort*)carve((size_t)64 * 192 * 2);
    // aliases (dead before their hosts are written):
    int2* bkt   = (int2*)B1b;  // E*8 = 12.8MB = N*128B; consumed by k_fill3 before lmul-1
    uint* histU = (uint*)Hb;   // 6.4MB; consumed by k_fill3 before gemm1 writes Hb
    (void)ws_size; (void)n_in; (void)out_size;

    int gW2 = (N + 7) / 8;
    int gPrep = GP + WTB + (N * 32 + 255) / 256;
    int gRS = (((N + 1) / 2) + 255) / 256;

    k_prep<<<gPrep, 256, 0, stream>>>(row, x, W1, W2, counts, xb, Wt1, Wt2, E, N, W);
    k_pscan<<<1, 512, 0, stream>>>(counts, bases, wtot, wbase, counter);
    k_pscatter<<<GP, 256, 0, stream>>>(row, col, bases, bkt, E, W);
    k_hist2<<<NW * BSL, 1024, 0, stream>>>(bkt, wbase, wtot, histU, N, W);
    k_rowsum2<<<gRS, 256, 0, stream>>>(histU, deg, dinv, startA, counter, N, W);
    k_fill3<<<NW * BSL, 1024, 0, stream>>>(bkt, wbase, wtot, startA, histU, dinv, ecc, N, W);

    int gG = 392;

    // layer 1
    k_lmul<<<gW2, 256, 0, stream>>>(startA, deg, ecc, dinv, xb, xb, B1b, N, 1.f, 0.f);
    k_lmul<<<gW2, 256, 0, stream>>>(startA, deg, ecc, dinv, B1b, xb, B2b, N, 2.f, -1.f);
    k_gemm_mfma<4, true, true><<<gG, 256, 0, stream>>>(xb, B1b, B2b, Wt1, b1, 50, Hb, nullptr, N);

    // layer 2
    k_lmul<<<gW2, 256, 0, stream>>>(startA, deg, ecc, dinv, Hb, Hb, B1b, N, 1.f, 0.f);
    k_lmul<<<gW2, 256, 0, stream>>>(startA, deg, ecc, dinv, B1b, Hb, B2b, N, 2.f, -1.f);
    k_gemm_mfma<3, false, false><<<gG, 256, 0, stream>>>(Hb, B1b, B2b, Wt2, b2, 40, nullptr, out, N);
}